// Round 1
// 62.148 us; speedup vs baseline: 1.0219x; 1.0219x over previous
//
#include <hip/hip_runtime.h>

#define RCR 5.2f
#define RCA 3.5f
#define PI_F 3.14159265358979323846f

// 2 waves per center atom: wave 0 = geometry/compaction + radial bins,
// wave 1 = angular pair loop (concurrent with radial).
__global__ __launch_bounds__(128) void aev_kernel(
    const int* __restrict__ species,
    const float* __restrict__ coords,
    float* __restrict__ out,
    int NA)   // total atoms = N*64
{
    const int blk  = blockIdx.x;
    const int n    = blk >> 6;   // molecule
    const int i    = blk & 63;   // center atom
    const int tid  = threadIdx.x;
    const int lane = tid & 63;
    const int wave = tid >> 6;

    __shared__ float sx[64], sy[64], sz[64];
    __shared__ int   ssp[64];
    // angular neighbor list, compacted at ballot time (no indirection later)
    __shared__ float adx[64], ady[64], adz[64], ads[64], afc[64];
    __shared__ int   asp[64];
    // radial lists, compacted PER SPECIES (lane s>>4 only walks its own list).
    // Row stride 65 words: row s starts at bank (65*s)%32 = s -> the four
    // broadcast groups hit 4 distinct banks, conflict-free.
    __shared__ float rds[4][65], rpre[4][65];
    __shared__ int   cnts[5];    // per-species radial counts + angular M
    __shared__ float s_ang[320];

    // ---- stage molecule (wave 0's first 64 lanes) + zero accumulator ----
    if (tid < 64) {
        const float* c = coords + (size_t)(n * 64) * 3;
        sx[tid]  = c[tid * 3 + 0];
        sy[tid]  = c[tid * 3 + 1];
        sz[tid]  = c[tid * 3 + 2];
        ssp[tid] = species[n * 64 + tid];
    }
    for (int f = tid; f < 320; f += 128) s_ang[f] = 0.0f;
    __syncthreads();

    // ---- wave 0: per-lane geometry + ballot compaction ----
    if (wave == 0) {
        const float xi  = sx[i], yi = sy[i], zi = sz[i];
        const float ddx = sx[lane] - xi;
        const float ddy = sy[lane] - yi;
        const float ddz = sz[lane] - zi;
        const float d   = sqrtf(ddx * ddx + ddy * ddy + ddz * ddz);
        const bool  isj = (lane != i);
        const int   sp  = ssp[lane];
        const float pre = 0.25f * (0.5f * __cosf((PI_F / RCR) * d) + 0.5f);
        const float fcv = 0.5f * __cosf((PI_F / RCA) * d) + 0.5f;

        // radial: compact by species -> 4x fewer iterations per shell-lane,
        // and direct (single-level) LDS reads in the hot loop
        const bool rpred = isj && (d <= RCR);
        #pragma unroll
        for (int s = 0; s < 4; s++) {
            const bool p = rpred && (sp == s);
            const unsigned long long b = __ballot(p);
            if (p) {
                const int pos = __popcll(b & ((1ull << lane) - 1ull));
                rds[s][pos]  = d;
                rpre[s][pos] = pre;
            }
            if (lane == 0) cnts[s] = __popcll(b);
        }

        // angular: compact all per-neighbor data now
        const bool apred = isj && (d <= RCA);
        const unsigned long long b = __ballot(apred);
        if (apred) {
            const int pos = __popcll(b & ((1ull << lane) - 1ull));
            adx[pos] = ddx; ady[pos] = ddy; adz[pos] = ddz;
            ads[pos] = d;   afc[pos] = fcv; asp[pos] = sp;
        }
        if (lane == 0) cnts[4] = __popcll(b);
    }
    __syncthreads();

    // ---- phase 2: radial (wave 0) || angular (wave 1), concurrent ----
    float racc = 0.0f;
    if (wave == 0) {
        const int   s   = lane >> 4;
        const float shf = 0.9f + 0.26875f * (float)(lane & 15);
        const int   mr  = cnts[s];
        #pragma unroll 4
        for (int jj = 0; jj < mr; jj++) {
            const float t = rds[s][jj] - shf;
            racc += rpre[s][jj] * __expf(-16.0f * t * t);
        }
    } else {
        const float CPHI[8] = { 0.98078528f,  0.83146961f,  0.55557023f,  0.19509032f,
                               -0.19509032f, -0.55557023f, -0.83146961f, -0.98078528f};
        const float SPHI[8] = { 0.19509032f,  0.55557023f,  0.83146961f,  0.98078528f,
                                0.98078528f,  0.83146961f,  0.55557023f,  0.19509032f};
        const float SHFA[4] = {0.9f, 1.55f, 2.2f, 2.85f};

        const int M = cnts[4];
        const int P = (M * (M - 1)) >> 1;   // unordered pairs jj>kk
        for (int q = lane; q < P; q += 64) {
            // triangular decode: q = jj*(jj-1)/2 + kk, kk < jj
            int jj = (int)((1.0f + sqrtf(1.0f + 8.0f * (float)q)) * 0.5f);
            while (((jj * (jj - 1)) >> 1) > q) --jj;
            while ((((jj + 1) * jj) >> 1) <= q) ++jj;
            const int kk = q - ((jj * (jj - 1)) >> 1);

            const float dij = ads[jj], dik = ads[kk];
            const float dot = adx[jj] * adx[kk] + ady[jj] * ady[kk] + adz[jj] * adz[kk];
            float cosv = 0.95f * dot * __builtin_amdgcn_rcpf(dij * dik);
            cosv = fminf(0.95f, fmaxf(-0.95f, cosv));
            const float sinv  = sqrtf(fmaxf(0.0f, 1.0f - cosv * cosv));
            const float base2 = 2.0f * afc[jj] * afc[kk];
            const float davg  = 0.5f * (dij + dik);
            const int s1 = asp[jj], s2 = asp[kk];
            const int smin = (s1 < s2) ? s1 : s2;
            const int smax = (s1 < s2) ? s2 : s1;
            const int pidx = ((smin * (7 - smin)) >> 1) + smax;

            float f2[4];
            #pragma unroll
            for (int a = 0; a < 4; a++) {
                const float t = davg - SHFA[a];
                f2[a] = base2 * __expf(-8.0f * t * t);
            }
            float t32z[8];
            #pragma unroll
            for (int z = 0; z < 8; z++) {
                const float w  = 0.5f + 0.5f * (cosv * CPHI[z] + sinv * SPHI[z]);
                const float t2 = w * w, t4 = t2 * t2, t8 = t4 * t4, t16 = t8 * t8;
                t32z[z] = t16 * t16;
            }
            float* dst = &s_ang[pidx * 32];
            #pragma unroll
            for (int a = 0; a < 4; a++)
                #pragma unroll
                for (int z = 0; z < 8; z++)
                    atomicAdd(&dst[a * 8 + z], f2[a] * t32z[z]);
        }
    }
    __syncthreads();

    // ---- write out: species head, then this atom's 384 AEV values ----
    const int atom = n * 64 + i;
    if (tid == 0) out[atom] = (float)ssp[i];
    float* dstg = out + NA + (size_t)atom * 384;
    if (wave == 0) dstg[lane] = racc;
    for (int u = tid; u < 320; u += 128) dstg[64 + u] = s_ang[u];
}

extern "C" void kernel_launch(void* const* d_in, const int* in_sizes, int n_in,
                              void* d_out, int out_size, void* d_ws, size_t ws_size,
                              hipStream_t stream) {
    const int*   species = (const int*)d_in[0];
    const float* coords  = (const float*)d_in[1];
    float*       out     = (float*)d_out;
    const int NA = in_sizes[0];          // N * 64 atoms (1024)
    aev_kernel<<<NA, 128, 0, stream>>>(species, coords, out, NA);
}